// Round 3
// baseline (319.895 us; speedup 1.0000x reference)
//
#include <hip/hip_runtime.h>

#define NTOK (8 * 16 * 32 * 32)  // 131072 tokens
#define NE 1024
#define ED 64
#define TPB 256                  // 4 waves per block
#define TOK_PER_BLK 64           // one token per lane
#define NCHUNK 4
#define CHUNK (NE / NCHUNK)      // 256 embeddings per wave

__global__ __launch_bounds__(TPB, 4) void vq_kernel(
    const float* __restrict__ z,
    const float* __restrict__ emb,
    float* __restrict__ zq_out,
    float* __restrict__ idx_out)
{
    __shared__ float s2[NE];
    __shared__ float red_d[NCHUNK][TOK_PER_BLK];
    __shared__ int   red_i[NCHUNK][TOK_PER_BLK];

    // ---- ||e||^2 for all 1024 embeddings (numpy-style 8-way pairwise) ----
    for (int e = threadIdx.x; e < NE; e += TPB) {
        const float* ep = emb + e * ED;
        float r0 = 0.f, r1 = 0.f, r2 = 0.f, r3 = 0.f;
        float r4 = 0.f, r5 = 0.f, r6 = 0.f, r7 = 0.f;
#pragma unroll
        for (int d = 0; d < ED; d += 8) {
            float v0 = ep[d + 0], v1 = ep[d + 1], v2 = ep[d + 2], v3 = ep[d + 3];
            float v4 = ep[d + 4], v5 = ep[d + 5], v6 = ep[d + 6], v7 = ep[d + 7];
            r0 += v0 * v0; r1 += v1 * v1; r2 += v2 * v2; r3 += v3 * v3;
            r4 += v4 * v4; r5 += v5 * v5; r6 += v6 * v6; r7 += v7 * v7;
        }
        s2[e] = ((r0 + r1) + (r2 + r3)) + ((r4 + r5) + (r6 + r7));
    }

    const int lane = threadIdx.x & 63;
    const int wave = __builtin_amdgcn_readfirstlane(threadIdx.x >> 6);
    const int t = blockIdx.x * TOK_PER_BLK + lane;

    // ---- token's z vector -> registers, PINNED so the compiler cannot
    //      rematerialize the global loads inside the e-loop (R2: VGPR=40
    //      proved it was re-loading z from memory 256 times per lane) ----
    float zr[ED];
    const float4* zp = (const float4*)(z + (size_t)t * ED);
#pragma unroll
    for (int i = 0; i < ED / 4; ++i) {
        float4 v = zp[i];
        zr[4 * i + 0] = v.x;
        zr[4 * i + 1] = v.y;
        zr[4 * i + 2] = v.z;
        zr[4 * i + 3] = v.w;
    }
#pragma unroll
    for (int i = 0; i < ED; ++i) {
        asm volatile("" : "+v"(zr[i]));  // opaque: forces VGPR residency
    }

    // ---- S1 = ||z||^2 (numpy-style 8-way pairwise) ----
    float r0 = 0.f, r1 = 0.f, r2 = 0.f, r3 = 0.f;
    float r4 = 0.f, r5 = 0.f, r6 = 0.f, r7 = 0.f;
#pragma unroll
    for (int d = 0; d < ED; d += 8) {
        r0 += zr[d + 0] * zr[d + 0];
        r1 += zr[d + 1] * zr[d + 1];
        r2 += zr[d + 2] * zr[d + 2];
        r3 += zr[d + 3] * zr[d + 3];
        r4 += zr[d + 4] * zr[d + 4];
        r5 += zr[d + 5] * zr[d + 5];
        r6 += zr[d + 6] * zr[d + 6];
        r7 += zr[d + 7] * zr[d + 7];
    }
    const float s1 = ((r0 + r1) + (r2 + r3)) + ((r4 + r5) + (r6 + r7));

    __syncthreads();  // s2 ready

    // ---- each wave scans its 256-embedding chunk (scalar emb loads) ----
    float best = 3.4e38f;
    int bi = 0;
    const int e0 = wave * CHUNK;
    for (int e = e0; e < e0 + CHUNK; ++e) {
        const float* ep = emb + e * ED;  // wave-uniform -> s_load
        float a0 = 0.f, a1 = 0.f, a2 = 0.f, a3 = 0.f;
#pragma unroll
        for (int d = 0; d < ED; d += 4) {
            a0 = fmaf(zr[d + 0], ep[d + 0], a0);
            a1 = fmaf(zr[d + 1], ep[d + 1], a1);
            a2 = fmaf(zr[d + 2], ep[d + 2], a2);
            a3 = fmaf(zr[d + 3], ep[d + 3], a3);
        }
        const float g = (a0 + a1) + (a2 + a3);
        const float dist = (s1 + s2[e]) - 2.0f * g;
        if (dist < best) { best = dist; bi = e; }  // strict < : first index wins
    }

    red_d[wave][lane] = best;
    red_i[wave][lane] = bi;
    __syncthreads();

    // ---- cross-chunk argmin (chunks in index order; strict < keeps lowest e) ----
    float wd = red_d[0][lane];
    int wi = red_i[0][lane];
#pragma unroll
    for (int c = 1; c < NCHUNK; ++c) {
        float d2 = red_d[c][lane];
        int i2 = red_i[c][lane];
        if (d2 < wd) { wd = d2; wi = i2; }
    }

    // ---- outputs: all 4 waves cooperate on z_q row copy ----
    const float4* eb = (const float4*)(emb + (size_t)wi * ED);
    float4* oq = (float4*)(zq_out + (size_t)t * ED);
#pragma unroll
    for (int i = 0; i < 4; ++i) oq[wave * 4 + i] = eb[wave * 4 + i];
    if (wave == 0) idx_out[t] = (float)wi;
}

extern "C" void kernel_launch(void* const* d_in, const int* in_sizes, int n_in,
                              void* d_out, int out_size, void* d_ws, size_t ws_size,
                              hipStream_t stream) {
    const float* z = (const float*)d_in[0];
    const float* emb = (const float*)d_in[1];
    float* out = (float*)d_out;
    float* zq = out;                       // 131072*64 floats
    float* idx = out + (size_t)NTOK * ED;  // 131072 floats

    vq_kernel<<<NTOK / TOK_PER_BLK, TPB, 0, stream>>>(z, emb, zq, idx);
}

// Round 4
// 177.914 us; speedup vs baseline: 1.7980x; 1.7980x over previous
//
#include <hip/hip_runtime.h>

typedef short short8 __attribute__((ext_vector_type(8)));
typedef float f32x4 __attribute__((ext_vector_type(4)));

#define NTOK (8 * 16 * 32 * 32)  // 131072 tokens
#define NE 1024
#define ED 64
#define TPB 256
#define MBLK 128                 // tokens per block
#define MWAVE 32                 // tokens per wave = 2 m-frags of 16
#define NCHUNK 8
#define ECHUNK 128               // embeddings staged per chunk
#define BSTRIDE 72               // halves per LDS row (64 + 8 pad -> 2-way banks, free)
#define WKEY (1 << 18)           // candidate window in key units (~3.9e-3 in dist)

__device__ __forceinline__ unsigned short bf16_rtne(float f) {
    unsigned u = __float_as_uint(f);
    return (unsigned short)((u + 0x7FFFu + ((u >> 16) & 1u)) >> 16);
}
__device__ __forceinline__ float bf16_to_f32(unsigned short h) {
    return __uint_as_float(((unsigned)h) << 16);
}

// EXACT distance — bit-identical structure to the R1 kernel that matched absmax 0.
__device__ float exact_dist(const float* __restrict__ z, const float* __restrict__ emb,
                            const float* s2ex, int t, int e) {
    const float* zt = z + (size_t)t * ED;
    const float* ep = emb + (size_t)e * ED;
    float r0 = 0.f, r1 = 0.f, r2 = 0.f, r3 = 0.f;
    float r4 = 0.f, r5 = 0.f, r6 = 0.f, r7 = 0.f;
    for (int d = 0; d < ED; d += 8) {
        r0 += zt[d + 0] * zt[d + 0];
        r1 += zt[d + 1] * zt[d + 1];
        r2 += zt[d + 2] * zt[d + 2];
        r3 += zt[d + 3] * zt[d + 3];
        r4 += zt[d + 4] * zt[d + 4];
        r5 += zt[d + 5] * zt[d + 5];
        r6 += zt[d + 6] * zt[d + 6];
        r7 += zt[d + 7] * zt[d + 7];
    }
    float s1 = ((r0 + r1) + (r2 + r3)) + ((r4 + r5) + (r6 + r7));
    float a0 = 0.f, a1 = 0.f, a2 = 0.f, a3 = 0.f;
    for (int d = 0; d < ED; d += 4) {
        a0 = fmaf(zt[d + 0], ep[d + 0], a0);
        a1 = fmaf(zt[d + 1], ep[d + 1], a1);
        a2 = fmaf(zt[d + 2], ep[d + 2], a2);
        a3 = fmaf(zt[d + 3], ep[d + 3], a3);
    }
    float g = (a0 + a1) + (a2 + a3);
    return (s1 + s2ex[e]) - 2.0f * g;
}

__global__ __launch_bounds__(TPB, 3) void vq_mfma(
    const float* __restrict__ z,
    const float* __restrict__ emb,
    float* __restrict__ zq_out,
    float* __restrict__ idx_out)
{
    __shared__ unsigned short bh[ECHUNK * BSTRIDE];  // e_hi bf16, padded rows
    __shared__ unsigned short bl[ECHUNK * BSTRIDE];  // e_lo bf16
    __shared__ float s2ex[NE];
    __shared__ int idx_lds[MBLK];

    const int tid = threadIdx.x;
    const int lane = tid & 63;
    const int wv = tid >> 6;
    const int col = lane & 15;     // MFMA col / A-row lane
    const int quad = lane >> 4;    // MFMA quad
    const int blockTok = blockIdx.x * MBLK;

    // ---- exact ||e||^2 (R1 formula) into LDS ----
    for (int e = tid; e < NE; e += TPB) {
        const float* ep = emb + e * ED;
        float r0 = 0.f, r1 = 0.f, r2 = 0.f, r3 = 0.f;
        float r4 = 0.f, r5 = 0.f, r6 = 0.f, r7 = 0.f;
#pragma unroll
        for (int d = 0; d < ED; d += 8) {
            float v0 = ep[d + 0], v1 = ep[d + 1], v2 = ep[d + 2], v3 = ep[d + 3];
            float v4 = ep[d + 4], v5 = ep[d + 5], v6 = ep[d + 6], v7 = ep[d + 7];
            r0 += v0 * v0; r1 += v1 * v1; r2 += v2 * v2; r3 += v3 * v3;
            r4 += v4 * v4; r5 += v5 * v5; r6 += v6 * v6; r7 += v7 * v7;
        }
        s2ex[e] = ((r0 + r1) + (r2 + r3)) + ((r4 + r5) + (r6 + r7));
    }

    // ---- A-fragments: this wave's 32 tokens as bf16 hi/lo (resident) ----
    // A layout (16x16x32): m = lane&15, k = quad*8 + j
    short8 Ah[2][2], Al[2][2];
#pragma unroll
    for (int mf = 0; mf < 2; ++mf) {
#pragma unroll
        for (int kf = 0; kf < 2; ++kf) {
            const float* zp = z + (size_t)(blockTok + wv * MWAVE + mf * 16 + col) * ED
                              + kf * 32 + quad * 8;
            float4 v0 = *(const float4*)zp;
            float4 v1 = *(const float4*)(zp + 4);
            float vs[8] = {v0.x, v0.y, v0.z, v0.w, v1.x, v1.y, v1.z, v1.w};
            short8 h, l;
#pragma unroll
            for (int j = 0; j < 8; ++j) {
                unsigned short hb = bf16_rtne(vs[j]);
                float hf = bf16_to_f32(hb);
                unsigned short lb = bf16_rtne(vs[j] - hf);
                h[j] = (short)hb;
                l[j] = (short)lb;
            }
            Ah[mf][kf] = h;
            Al[mf][kf] = l;
        }
    }

    int aK[2][4], bK[2][4];  // per-lane top-2 keys per (m-frag, reg)
#pragma unroll
    for (int mf = 0; mf < 2; ++mf)
#pragma unroll
        for (int r = 0; r < 4; ++r) { aK[mf][r] = 0x7FFFFFFF; bK[mf][r] = 0x7FFFFFFF; }

    __syncthreads();  // s2ex ready

    const float4* emb_f4 = (const float4*)emb;

    for (int c = 0; c < NCHUNK; ++c) {
        __syncthreads();  // previous chunk's reads done before overwrite
        // ---- stage 128 embeddings as hi/lo bf16 into LDS ----
#pragma unroll
        for (int i = 0; i < 8; ++i) {
            int item = tid + i * TPB;        // 2048 float4s
            int el = item >> 4, f4 = item & 15;
            float4 v = emb_f4[(size_t)(c * ECHUNK + el) * 16 + f4];
            float vv[4] = {v.x, v.y, v.z, v.w};
            unsigned hx[4], lx[4];
#pragma unroll
            for (int j = 0; j < 4; ++j) {
                unsigned short hb = bf16_rtne(vv[j]);
                float hf = bf16_to_f32(hb);
                unsigned short lb = bf16_rtne(vv[j] - hf);
                hx[j] = hb; lx[j] = lb;
            }
            uint2 hw = make_uint2(hx[0] | (hx[1] << 16), hx[2] | (hx[3] << 16));
            uint2 lw = make_uint2(lx[0] | (lx[1] << 16), lx[2] | (lx[3] << 16));
            *(uint2*)&bh[el * BSTRIDE + f4 * 4] = hw;
            *(uint2*)&bl[el * BSTRIDE + f4 * 4] = lw;
        }
        __syncthreads();

        // ---- MFMA over 8 n-tiles of 16 embeddings ----
#pragma unroll
        for (int nt = 0; nt < ECHUNK / 16; ++nt) {
            const int e = c * ECHUNK + nt * 16 + col;
            const float s2s = s2ex[e] * 65536.0f;
            const int rowoff = (nt * 16 + col) * BSTRIDE + quad * 8;
            short8 Bh0 = *(const short8*)&bh[rowoff];
            short8 Bh1 = *(const short8*)&bh[rowoff + 32];
            short8 Bl0 = *(const short8*)&bl[rowoff];
            short8 Bl1 = *(const short8*)&bl[rowoff + 32];
#pragma unroll
            for (int mf = 0; mf < 2; ++mf) {
                f32x4 cc = {0.f, 0.f, 0.f, 0.f};
                cc = __builtin_amdgcn_mfma_f32_16x16x32_bf16(Ah[mf][0], Bh0, cc, 0, 0, 0);
                cc = __builtin_amdgcn_mfma_f32_16x16x32_bf16(Ah[mf][1], Bh1, cc, 0, 0, 0);
                cc = __builtin_amdgcn_mfma_f32_16x16x32_bf16(Al[mf][0], Bh0, cc, 0, 0, 0);
                cc = __builtin_amdgcn_mfma_f32_16x16x32_bf16(Al[mf][1], Bh1, cc, 0, 0, 0);
                cc = __builtin_amdgcn_mfma_f32_16x16x32_bf16(Ah[mf][0], Bl0, cc, 0, 0, 0);
                cc = __builtin_amdgcn_mfma_f32_16x16x32_bf16(Ah[mf][1], Bl1, cc, 0, 0, 0);
#pragma unroll
                for (int r = 0; r < 4; ++r) {
                    float p2 = fmaf(cc[r], -131072.0f, s2s);  // (s2 - 2g) * 65536
                    p2 = fminf(fmaxf(p2, -1.0e6f), 1.0e6f);   // keep *1024 in int range
                    int key = ((int)p2) * 1024 + e;            // unique, monotone, tie->low e
                    int t1 = min(aK[mf][r], key);
                    bK[mf][r] = min(bK[mf][r], max(aK[mf][r], key));
                    aK[mf][r] = t1;
                }
            }
        }
    }

    // ---- phase B: resolve argmin per token ----
#pragma unroll
    for (int mf = 0; mf < 2; ++mf) {
#pragma unroll
        for (int r = 0; r < 4; ++r) {
            const int a0 = aK[mf][r], b0 = bK[mf][r];
            int A = a0, B = b0;
#pragma unroll
            for (int off = 1; off < 16; off <<= 1) {
                int A2 = __shfl_xor(A, off);
                int B2 = __shfl_xor(B, off);
                int lo = min(A, A2), hi = max(A, A2);
                B = min(min(B, B2), hi);
                A = lo;
            }
            int winner = A & 1023;
            if (B - A <= WKEY) {  // contested: exact fp32 re-check of candidates
                const int t = blockTok + wv * MWAVE + mf * 16 + quad * 4 + r;
                float dbest = 3.4e38f;
                int ibest = 1 << 30;
                if (a0 <= A + WKEY) {
                    int e = a0 & 1023;
                    float d = exact_dist(z, emb, s2ex, t, e);
                    if (d < dbest || (d == dbest && e < ibest)) { dbest = d; ibest = e; }
                }
                if (b0 <= A + WKEY) {
                    int e = b0 & 1023;
                    float d = exact_dist(z, emb, s2ex, t, e);
                    if (d < dbest || (d == dbest && e < ibest)) { dbest = d; ibest = e; }
                }
#pragma unroll
                for (int off = 1; off < 16; off <<= 1) {
                    float d2 = __shfl_xor(dbest, off);
                    int i2 = __shfl_xor(ibest, off);
                    if (d2 < dbest || (d2 == dbest && i2 < ibest)) { dbest = d2; ibest = i2; }
                }
                winner = ibest;
            }
            if (col == 0) idx_lds[wv * MWAVE + mf * 16 + quad * 4 + r] = winner;
        }
    }

    __syncthreads();

    // ---- outputs ----
    if (tid < MBLK) idx_out[blockTok + tid] = (float)idx_lds[tid];
    float4* zq_f4 = (float4*)zq_out;
#pragma unroll
    for (int i = 0; i < MBLK * 16 / TPB; ++i) {  // 8 iters
        int item = tid + i * TPB;
        int tl = item >> 4, f4 = item & 15;
        int wi = idx_lds[tl];
        zq_f4[(size_t)(blockTok + tl) * 16 + f4] = emb_f4[(size_t)wi * 16 + f4];
    }
}

extern "C" void kernel_launch(void* const* d_in, const int* in_sizes, int n_in,
                              void* d_out, int out_size, void* d_ws, size_t ws_size,
                              hipStream_t stream) {
    const float* z = (const float*)d_in[0];
    const float* emb = (const float*)d_in[1];
    float* out = (float*)d_out;
    float* zq = out;                       // 131072*64 floats
    float* idx = out + (size_t)NTOK * ED;  // 131072 floats

    vq_mfma<<<NTOK / MBLK, TPB, 0, stream>>>(z, emb, zq, idx);
}

// Round 6
// 165.084 us; speedup vs baseline: 1.9378x; 1.0777x over previous
//
#include <hip/hip_runtime.h>

typedef short short8 __attribute__((ext_vector_type(8)));
typedef float f32x4 __attribute__((ext_vector_type(4)));

#define NTOK (8 * 16 * 32 * 32)  // 131072 tokens
#define NE 1024
#define ED 64
#define TPB 256
#define MBLK 256                 // tokens per block = 4 waves x 64
#define WKEY (1 << 18)           // candidate window in key units (~3.9e-3 in dist)
#define SCALE (-131072.0f)       // -2^17: exact po2 scale — applied to B ONLY

__device__ __forceinline__ unsigned short bf16_rtne(float f) {
    unsigned u = __float_as_uint(f);
    return (unsigned short)((u + 0x7FFFu + ((u >> 16) & 1u)) >> 16);
}
__device__ __forceinline__ float bf16_to_f32(unsigned short h) {
    return __uint_as_float(((unsigned)h) << 16);
}

// EXACT distance — identical structure/order to the R1 kernel (absmax 0 vs numpy).
__device__ float exact_dist(const float* __restrict__ z, const float* __restrict__ emb,
                            int t, int e) {
    const float* zt = z + (size_t)t * ED;
    const float* ep = emb + (size_t)e * ED;
    float r0 = 0.f, r1 = 0.f, r2 = 0.f, r3 = 0.f;
    float r4 = 0.f, r5 = 0.f, r6 = 0.f, r7 = 0.f;
    for (int d = 0; d < ED; d += 8) {
        r0 += zt[d + 0] * zt[d + 0];
        r1 += zt[d + 1] * zt[d + 1];
        r2 += zt[d + 2] * zt[d + 2];
        r3 += zt[d + 3] * zt[d + 3];
        r4 += zt[d + 4] * zt[d + 4];
        r5 += zt[d + 5] * zt[d + 5];
        r6 += zt[d + 6] * zt[d + 6];
        r7 += zt[d + 7] * zt[d + 7];
    }
    float s1 = ((r0 + r1) + (r2 + r3)) + ((r4 + r5) + (r6 + r7));
    float q0 = 0.f, q1 = 0.f, q2 = 0.f, q3 = 0.f;
    float q4 = 0.f, q5 = 0.f, q6 = 0.f, q7 = 0.f;
    for (int d = 0; d < ED; d += 8) {
        float v0 = ep[d + 0], v1 = ep[d + 1], v2 = ep[d + 2], v3 = ep[d + 3];
        float v4 = ep[d + 4], v5 = ep[d + 5], v6 = ep[d + 6], v7 = ep[d + 7];
        q0 += v0 * v0; q1 += v1 * v1; q2 += v2 * v2; q3 += v3 * v3;
        q4 += v4 * v4; q5 += v5 * v5; q6 += v6 * v6; q7 += v7 * v7;
    }
    float s2 = ((q0 + q1) + (q2 + q3)) + ((q4 + q5) + (q6 + q7));
    float a0 = 0.f, a1 = 0.f, a2 = 0.f, a3 = 0.f;
    for (int d = 0; d < ED; d += 4) {
        a0 = fmaf(zt[d + 0], ep[d + 0], a0);
        a1 = fmaf(zt[d + 1], ep[d + 1], a1);
        a2 = fmaf(zt[d + 2], ep[d + 2], a2);
        a3 = fmaf(zt[d + 3], ep[d + 3], a3);
    }
    float g = (a0 + a1) + (a2 + a3);
    return (s1 + s2) - 2.0f * g;
}

// ---- prep: B-fragments (hi/lo bf16, pre-scaled by -2^17, MFMA-fragment order)
//      + s2s = ||e||^2 * 65536 ----
__global__ __launch_bounds__(TPB) void vq_prep(
    const float* __restrict__ emb,
    unsigned short* __restrict__ bfH,
    unsigned short* __restrict__ bfL,
    float* __restrict__ s2s)
{
    const int f = blockIdx.x * TPB + threadIdx.x;  // 0..8191 fragment id
    const int col = f & 15;
    const int quad = (f >> 4) & 3;
    const int kb = (f >> 6) & 1;
    const int nt = f >> 7;
    const int e = nt * 16 + col;
    const int k0 = kb * 32 + quad * 8;

    const float* p = emb + (size_t)e * ED + k0;
    float4 v0 = *(const float4*)p;
    float4 v1 = *(const float4*)(p + 4);
    float vs[8] = {v0.x, v0.y, v0.z, v0.w, v1.x, v1.y, v1.z, v1.w};
    short8 h, l;
#pragma unroll
    for (int j = 0; j < 8; ++j) {
        float x = vs[j] * SCALE;              // exact po2 scaling (B side only!)
        unsigned short hb = bf16_rtne(x);
        float hf = bf16_to_f32(hb);
        unsigned short lb = bf16_rtne(x - hf);
        h[j] = (short)hb;
        l[j] = (short)lb;
    }
    *(short8*)&bfH[(size_t)f * 8] = h;
    *(short8*)&bfL[(size_t)f * 8] = l;

    if (f < NE) {  // s2 * 65536 (exact po2 scale of pairwise sum)
        const float* ep = emb + (size_t)f * ED;
        float q0 = 0.f, q1 = 0.f, q2 = 0.f, q3 = 0.f;
        float q4 = 0.f, q5 = 0.f, q6 = 0.f, q7 = 0.f;
#pragma unroll
        for (int d = 0; d < ED; d += 8) {
            float w0 = ep[d + 0], w1 = ep[d + 1], w2 = ep[d + 2], w3 = ep[d + 3];
            float w4 = ep[d + 4], w5 = ep[d + 5], w6 = ep[d + 6], w7 = ep[d + 7];
            q0 += w0 * w0; q1 += w1 * w1; q2 += w2 * w2; q3 += w3 * w3;
            q4 += w4 * w4; q5 += w5 * w5; q6 += w6 * w6; q7 += w7 * w7;
        }
        float s2 = ((q0 + q1) + (q2 + q3)) + ((q4 + q5) + (q6 + q7));
        s2s[f] = s2 * 65536.0f;
    }
}

__global__ __launch_bounds__(TPB, 3) void vq_main(
    const float* __restrict__ z,
    const float* __restrict__ emb,
    const unsigned short* __restrict__ bfH,
    const unsigned short* __restrict__ bfL,
    const float* __restrict__ s2s_g,
    float* __restrict__ zq_out,
    float* __restrict__ idx_out)
{
    __shared__ float s2L[NE];
    __shared__ int idx_lds[MBLK];

    const int tid = threadIdx.x;
    const int lane = tid & 63;
    const int wv = __builtin_amdgcn_readfirstlane(tid >> 6);
    const int col = lane & 15;
    const int quad = lane >> 4;
    const int blockTok = blockIdx.x * MBLK;

    for (int i = tid; i < NE; i += TPB) s2L[i] = s2s_g[i];

    // ---- A-fragments: 64 tokens per wave (4 m-frags), hi/lo bf16, UNSCALED
    //      (R5 bug: scaling both A and B gave +2^34*g -> garbage keys) ----
    short8 Ah[4][2], Al[4][2];
#pragma unroll
    for (int mf = 0; mf < 4; ++mf) {
#pragma unroll
        for (int kf = 0; kf < 2; ++kf) {
            const float* zp = z + (size_t)(blockTok + wv * 64 + mf * 16 + col) * ED
                              + kf * 32 + quad * 8;
            float4 v0 = *(const float4*)zp;
            float4 v1 = *(const float4*)(zp + 4);
            float vs[8] = {v0.x, v0.y, v0.z, v0.w, v1.x, v1.y, v1.z, v1.w};
            short8 h, l;
#pragma unroll
            for (int j = 0; j < 8; ++j) {
                float x = vs[j];              // NO scale on A
                unsigned short hb = bf16_rtne(x);
                float hf = bf16_to_f32(hb);
                unsigned short lb = bf16_rtne(x - hf);
                h[j] = (short)hb;
                l[j] = (short)lb;
            }
            Ah[mf][kf] = h;
            Al[mf][kf] = l;
        }
    }

    int aK[4][4], bK[4][4];
#pragma unroll
    for (int mf = 0; mf < 4; ++mf)
#pragma unroll
        for (int r = 0; r < 4; ++r) { aK[mf][r] = 0x7FFFFFFF; bK[mf][r] = 0x7FFFFFFF; }

    __syncthreads();  // s2L ready — last barrier before the hot loop

    const short8* bh8 = (const short8*)bfH;
    const short8* bl8 = (const short8*)bfL;

    // ---- hot loop: no barriers, no LDS staging, no conversions ----
    for (int nt = 0; nt < 64; ++nt) {
        const float s2v = s2L[nt * 16 + col];
        const int e = nt * 16 + col;
        short8 Bh0 = bh8[(nt * 2 + 0) * 64 + lane];  // coalesced 1KB/wave from L1/L2
        short8 Bh1 = bh8[(nt * 2 + 1) * 64 + lane];
        short8 Bl0 = bl8[(nt * 2 + 0) * 64 + lane];
        short8 Bl1 = bl8[(nt * 2 + 1) * 64 + lane];
#pragma unroll
        for (int mf = 0; mf < 4; ++mf) {
            f32x4 cc = {s2v, s2v, s2v, s2v};  // acc = s2*2^16 + A·(-2^17 e) = 2^16(s2-2g)
            cc = __builtin_amdgcn_mfma_f32_16x16x32_bf16(Ah[mf][0], Bh0, cc, 0, 0, 0);
            cc = __builtin_amdgcn_mfma_f32_16x16x32_bf16(Ah[mf][1], Bh1, cc, 0, 0, 0);
            cc = __builtin_amdgcn_mfma_f32_16x16x32_bf16(Al[mf][0], Bh0, cc, 0, 0, 0);
            cc = __builtin_amdgcn_mfma_f32_16x16x32_bf16(Al[mf][1], Bh1, cc, 0, 0, 0);
            cc = __builtin_amdgcn_mfma_f32_16x16x32_bf16(Ah[mf][0], Bl0, cc, 0, 0, 0);
            cc = __builtin_amdgcn_mfma_f32_16x16x32_bf16(Ah[mf][1], Bl1, cc, 0, 0, 0);
#pragma unroll
            for (int r = 0; r < 4; ++r) {
                float p2 = fminf(fmaxf(cc[r], -1.0e6f), 1.0e6f);  // never binds; int-safe
                int key = ((int)p2) * 1024 + e;  // unique, monotone, tie->low e
                int t1 = min(aK[mf][r], key);
                bK[mf][r] = min(bK[mf][r], max(aK[mf][r], key));
                aK[mf][r] = t1;
            }
        }
    }

    // ---- phase B: resolve argmin per token (16-lane groups, as R4) ----
#pragma unroll
    for (int mf = 0; mf < 4; ++mf) {
#pragma unroll
        for (int r = 0; r < 4; ++r) {
            const int a0 = aK[mf][r], b0 = bK[mf][r];
            int A = a0, B = b0;
#pragma unroll
            for (int off = 1; off < 16; off <<= 1) {
                int A2 = __shfl_xor(A, off);
                int B2 = __shfl_xor(B, off);
                int lo = min(A, A2), hi = max(A, A2);
                B = min(min(B, B2), hi);
                A = lo;
            }
            int winner = A & 1023;
            if (B - A <= WKEY) {  // contested: exact fp32 re-check of candidates
                const int t = blockTok + wv * 64 + mf * 16 + quad * 4 + r;
                float dbest = 3.4e38f;
                int ibest = 1 << 30;
                if (a0 <= A + WKEY) {
                    int e = a0 & 1023;
                    float d = exact_dist(z, emb, t, e);
                    if (d < dbest || (d == dbest && e < ibest)) { dbest = d; ibest = e; }
                }
                if (b0 <= A + WKEY) {
                    int e = b0 & 1023;
                    float d = exact_dist(z, emb, t, e);
                    if (d < dbest || (d == dbest && e < ibest)) { dbest = d; ibest = e; }
                }
#pragma unroll
                for (int off = 1; off < 16; off <<= 1) {
                    float d2 = __shfl_xor(dbest, off);
                    int i2 = __shfl_xor(ibest, off);
                    if (d2 < dbest || (d2 == dbest && i2 < ibest)) { dbest = d2; ibest = i2; }
                }
                winner = ibest;
            }
            if (col == 0) idx_lds[wv * 64 + mf * 16 + quad * 4 + r] = winner;
        }
    }

    __syncthreads();

    // ---- outputs ----
    idx_out[blockTok + tid] = (float)idx_lds[tid];
    const float4* emb_f4 = (const float4*)emb;
    float4* zq_f4 = (float4*)zq_out;
#pragma unroll
    for (int i = 0; i < MBLK * 16 / TPB; ++i) {  // 16 iters
        int item = tid + i * TPB;
        int tl = item >> 4, f4 = item & 15;
        int wi = idx_lds[tl];
        zq_f4[(size_t)(blockTok + tl) * 16 + f4] = emb_f4[(size_t)wi * 16 + f4];
    }
}

extern "C" void kernel_launch(void* const* d_in, const int* in_sizes, int n_in,
                              void* d_out, int out_size, void* d_ws, size_t ws_size,
                              hipStream_t stream) {
    const float* z = (const float*)d_in[0];
    const float* emb = (const float*)d_in[1];
    float* out = (float*)d_out;
    float* zq = out;                       // 131072*64 floats
    float* idx = out + (size_t)NTOK * ED;  // 131072 floats

    // ws layout: s2s (4KB) | bfH (128KB) | bfL (128KB)
    char* ws = (char*)d_ws;
    float* s2s = (float*)ws;
    unsigned short* bfH = (unsigned short*)(ws + 4096);
    unsigned short* bfL = (unsigned short*)(ws + 4096 + 131072);

    vq_prep<<<32, TPB, 0, stream>>>(emb, bfH, bfL, s2s);
    vq_main<<<NTOK / MBLK, TPB, 0, stream>>>(z, emb, bfH, bfL, s2s, zq, idx);
}

// Round 7
// 158.273 us; speedup vs baseline: 2.0212x; 1.0430x over previous
//
#include <hip/hip_runtime.h>

typedef short short8 __attribute__((ext_vector_type(8)));
typedef float f32x4 __attribute__((ext_vector_type(4)));

#define NTOK (8 * 16 * 32 * 32)  // 131072 tokens
#define NE 1024
#define ED 64
#define TPB 256
#define MBLK 128                 // tokens per block = 4 waves x 32
#define NMF 2                    // m-frags per wave (32 tokens)
#define WKEY (1 << 18)           // candidate window in key units (~3.9e-3 in dist)
#define SCALE (-131072.0f)       // -2^17: exact po2 scale — applied to B ONLY

__device__ __forceinline__ unsigned short bf16_rtne(float f) {
    unsigned u = __float_as_uint(f);
    return (unsigned short)((u + 0x7FFFu + ((u >> 16) & 1u)) >> 16);
}
__device__ __forceinline__ float bf16_to_f32(unsigned short h) {
    return __uint_as_float(((unsigned)h) << 16);
}

// EXACT distance — identical structure/order to the R1 kernel (absmax 0 vs numpy).
__device__ float exact_dist(const float* __restrict__ z, const float* __restrict__ emb,
                            int t, int e) {
    const float* zt = z + (size_t)t * ED;
    const float* ep = emb + (size_t)e * ED;
    float r0 = 0.f, r1 = 0.f, r2 = 0.f, r3 = 0.f;
    float r4 = 0.f, r5 = 0.f, r6 = 0.f, r7 = 0.f;
    for (int d = 0; d < ED; d += 8) {
        r0 += zt[d + 0] * zt[d + 0];
        r1 += zt[d + 1] * zt[d + 1];
        r2 += zt[d + 2] * zt[d + 2];
        r3 += zt[d + 3] * zt[d + 3];
        r4 += zt[d + 4] * zt[d + 4];
        r5 += zt[d + 5] * zt[d + 5];
        r6 += zt[d + 6] * zt[d + 6];
        r7 += zt[d + 7] * zt[d + 7];
    }
    float s1 = ((r0 + r1) + (r2 + r3)) + ((r4 + r5) + (r6 + r7));
    float q0 = 0.f, q1 = 0.f, q2 = 0.f, q3 = 0.f;
    float q4 = 0.f, q5 = 0.f, q6 = 0.f, q7 = 0.f;
    for (int d = 0; d < ED; d += 8) {
        float v0 = ep[d + 0], v1 = ep[d + 1], v2 = ep[d + 2], v3 = ep[d + 3];
        float v4 = ep[d + 4], v5 = ep[d + 5], v6 = ep[d + 6], v7 = ep[d + 7];
        q0 += v0 * v0; q1 += v1 * v1; q2 += v2 * v2; q3 += v3 * v3;
        q4 += v4 * v4; q5 += v5 * v5; q6 += v6 * v6; q7 += v7 * v7;
    }
    float s2 = ((q0 + q1) + (q2 + q3)) + ((q4 + q5) + (q6 + q7));
    float a0 = 0.f, a1 = 0.f, a2 = 0.f, a3 = 0.f;
    for (int d = 0; d < ED; d += 4) {
        a0 = fmaf(zt[d + 0], ep[d + 0], a0);
        a1 = fmaf(zt[d + 1], ep[d + 1], a1);
        a2 = fmaf(zt[d + 2], ep[d + 2], a2);
        a3 = fmaf(zt[d + 3], ep[d + 3], a3);
    }
    float g = (a0 + a1) + (a2 + a3);
    return (s1 + s2) - 2.0f * g;
}

// ---- prep: B-fragments (hi/lo bf16, pre-scaled by -2^17, MFMA-fragment order)
//      + s2s = ||e||^2 * 65536.  64 blocks x 128 thr; s2 work spread evenly ----
__global__ __launch_bounds__(128) void vq_prep(
    const float* __restrict__ emb,
    unsigned short* __restrict__ bfH,
    unsigned short* __restrict__ bfL,
    float* __restrict__ s2s)
{
    const int f = blockIdx.x * 128 + threadIdx.x;  // 0..8191 fragment id
    const int col = f & 15;
    const int quad = (f >> 4) & 3;
    const int kb = (f >> 6) & 1;
    const int nt = f >> 7;
    const int e = nt * 16 + col;
    const int k0 = kb * 32 + quad * 8;

    const float* p = emb + (size_t)e * ED + k0;
    float4 v0 = *(const float4*)p;
    float4 v1 = *(const float4*)(p + 4);
    float vs[8] = {v0.x, v0.y, v0.z, v0.w, v1.x, v1.y, v1.z, v1.w};
    short8 h, l;
#pragma unroll
    for (int j = 0; j < 8; ++j) {
        float x = vs[j] * SCALE;              // exact po2 scaling (B side only!)
        unsigned short hb = bf16_rtne(x);
        float hf = bf16_to_f32(hb);
        unsigned short lb = bf16_rtne(x - hf);
        h[j] = (short)hb;
        l[j] = (short)lb;
    }
    *(short8*)&bfH[(size_t)f * 8] = h;
    *(short8*)&bfL[(size_t)f * 8] = l;

    if ((f & 7) == 0) {  // 1024 s2-threads spread across all 64 blocks
        const int e2 = f >> 3;
        const float* ep = emb + (size_t)e2 * ED;
        float q0 = 0.f, q1 = 0.f, q2 = 0.f, q3 = 0.f;
        float q4 = 0.f, q5 = 0.f, q6 = 0.f, q7 = 0.f;
#pragma unroll
        for (int d = 0; d < ED; d += 8) {
            float w0 = ep[d + 0], w1 = ep[d + 1], w2 = ep[d + 2], w3 = ep[d + 3];
            float w4 = ep[d + 4], w5 = ep[d + 5], w6 = ep[d + 6], w7 = ep[d + 7];
            q0 += w0 * w0; q1 += w1 * w1; q2 += w2 * w2; q3 += w3 * w3;
            q4 += w4 * w4; q5 += w5 * w5; q6 += w6 * w6; q7 += w7 * w7;
        }
        float s2 = ((q0 + q1) + (q2 + q3)) + ((q4 + q5) + (q6 + q7));
        s2s[e2] = s2 * 65536.0f;
    }
}

__global__ __launch_bounds__(TPB, 4) void vq_main(
    const float* __restrict__ z,
    const float* __restrict__ emb,
    const unsigned short* __restrict__ bfH,
    const unsigned short* __restrict__ bfL,
    const float* __restrict__ s2s_g,
    float* __restrict__ zq_out,
    float* __restrict__ idx_out)
{
    __shared__ float s2L[NE];
    __shared__ int idx_lds[MBLK];

    const int tid = threadIdx.x;
    const int lane = tid & 63;
    const int wv = __builtin_amdgcn_readfirstlane(tid >> 6);
    const int col = lane & 15;
    const int quad = lane >> 4;
    const int blockTok = blockIdx.x * MBLK;

    for (int i = tid; i < NE; i += TPB) s2L[i] = s2s_g[i];

    // ---- A-fragments: 32 tokens per wave (2 m-frags), hi/lo bf16, UNSCALED ----
    short8 Ah[NMF][2], Al[NMF][2];
#pragma unroll
    for (int mf = 0; mf < NMF; ++mf) {
#pragma unroll
        for (int kf = 0; kf < 2; ++kf) {
            const float* zp = z + (size_t)(blockTok + wv * 32 + mf * 16 + col) * ED
                              + kf * 32 + quad * 8;
            float4 v0 = *(const float4*)zp;
            float4 v1 = *(const float4*)(zp + 4);
            float vs[8] = {v0.x, v0.y, v0.z, v0.w, v1.x, v1.y, v1.z, v1.w};
            short8 h, l;
#pragma unroll
            for (int j = 0; j < 8; ++j) {
                float x = vs[j];              // NO scale on A
                unsigned short hb = bf16_rtne(x);
                float hf = bf16_to_f32(hb);
                unsigned short lb = bf16_rtne(x - hf);
                h[j] = (short)hb;
                l[j] = (short)lb;
            }
            Ah[mf][kf] = h;
            Al[mf][kf] = l;
        }
    }

    int aK[NMF][4], bK[NMF][4];
#pragma unroll
    for (int mf = 0; mf < NMF; ++mf)
#pragma unroll
        for (int r = 0; r < 4; ++r) { aK[mf][r] = 0x7FFFFFFF; bK[mf][r] = 0x7FFFFFFF; }

    __syncthreads();  // s2L ready — last barrier before the hot loop

    const short8* bh8 = (const short8*)bfH;
    const short8* bl8 = (const short8*)bfL;

    // ---- software-pipelined hot loop: prefetch nt+1's B while computing nt ----
    short8 Bh0 = bh8[lane], Bh1 = bh8[64 + lane];
    short8 Bl0 = bl8[lane], Bl1 = bl8[64 + lane];
#pragma unroll 4
    for (int nt = 0; nt < 64; ++nt) {
        const int nbase = (((nt + 1) & 63) * 2) * 64 + lane;  // wraps; harmless
        short8 nh0 = bh8[nbase], nh1 = bh8[nbase + 64];
        short8 nl0 = bl8[nbase], nl1 = bl8[nbase + 64];

        const float s2v = s2L[nt * 16 + col];
        const int e = nt * 16 + col;
#pragma unroll
        for (int mf = 0; mf < NMF; ++mf) {
            f32x4 cc = {s2v, s2v, s2v, s2v};  // acc = s2*2^16 + A·(-2^17 e) = 2^16(s2-2g)
            cc = __builtin_amdgcn_mfma_f32_16x16x32_bf16(Ah[mf][0], Bh0, cc, 0, 0, 0);
            cc = __builtin_amdgcn_mfma_f32_16x16x32_bf16(Ah[mf][1], Bh1, cc, 0, 0, 0);
            cc = __builtin_amdgcn_mfma_f32_16x16x32_bf16(Al[mf][0], Bh0, cc, 0, 0, 0);
            cc = __builtin_amdgcn_mfma_f32_16x16x32_bf16(Al[mf][1], Bh1, cc, 0, 0, 0);
            cc = __builtin_amdgcn_mfma_f32_16x16x32_bf16(Ah[mf][0], Bl0, cc, 0, 0, 0);
            cc = __builtin_amdgcn_mfma_f32_16x16x32_bf16(Ah[mf][1], Bl1, cc, 0, 0, 0);
#pragma unroll
            for (int r = 0; r < 4; ++r) {
                float p2 = fminf(fmaxf(cc[r], -1.0e6f), 1.0e6f);  // int-safety clamp
                int key = ((int)p2) * 1024 + e;  // unique, monotone, tie->low e
                int t1 = min(aK[mf][r], key);
                bK[mf][r] = min(bK[mf][r], max(aK[mf][r], key));
                aK[mf][r] = t1;
            }
        }
        Bh0 = nh0; Bh1 = nh1; Bl0 = nl0; Bl1 = nl1;
    }

    // ---- phase B: resolve argmin per token (16-lane groups) ----
#pragma unroll
    for (int mf = 0; mf < NMF; ++mf) {
#pragma unroll
        for (int r = 0; r < 4; ++r) {
            const int a0 = aK[mf][r], b0 = bK[mf][r];
            int A = a0, B = b0;
#pragma unroll
            for (int off = 1; off < 16; off <<= 1) {
                int A2 = __shfl_xor(A, off);
                int B2 = __shfl_xor(B, off);
                int lo = min(A, A2), hi = max(A, A2);
                B = min(min(B, B2), hi);
                A = lo;
            }
            int winner = A & 1023;
            if (B - A <= WKEY) {  // contested: exact fp32 re-check of candidates
                const int t = blockTok + wv * 32 + mf * 16 + quad * 4 + r;
                float dbest = 3.4e38f;
                int ibest = 1 << 30;
                if (a0 <= A + WKEY) {
                    int e = a0 & 1023;
                    float d = exact_dist(z, emb, t, e);
                    if (d < dbest || (d == dbest && e < ibest)) { dbest = d; ibest = e; }
                }
                if (b0 <= A + WKEY) {
                    int e = b0 & 1023;
                    float d = exact_dist(z, emb, t, e);
                    if (d < dbest || (d == dbest && e < ibest)) { dbest = d; ibest = e; }
                }
#pragma unroll
                for (int off = 1; off < 16; off <<= 1) {
                    float d2 = __shfl_xor(dbest, off);
                    int i2 = __shfl_xor(ibest, off);
                    if (d2 < dbest || (d2 == dbest && i2 < ibest)) { dbest = d2; ibest = i2; }
                }
                winner = ibest;
            }
            if (col == 0) idx_lds[wv * 32 + mf * 16 + quad * 4 + r] = winner;
        }
    }

    __syncthreads();

    // ---- outputs ----
    if (tid < MBLK) idx_out[blockTok + tid] = (float)idx_lds[tid];
    const float4* emb_f4 = (const float4*)emb;
    float4* zq_f4 = (float4*)zq_out;
#pragma unroll
    for (int i = 0; i < MBLK * 16 / TPB; ++i) {  // 8 iters
        int item = tid + i * TPB;
        int tl = item >> 4, f4 = item & 15;
        int wi = idx_lds[tl];
        zq_f4[(size_t)(blockTok + tl) * 16 + f4] = emb_f4[(size_t)wi * 16 + f4];
    }
}

extern "C" void kernel_launch(void* const* d_in, const int* in_sizes, int n_in,
                              void* d_out, int out_size, void* d_ws, size_t ws_size,
                              hipStream_t stream) {
    const float* z = (const float*)d_in[0];
    const float* emb = (const float*)d_in[1];
    float* out = (float*)d_out;
    float* zq = out;                       // 131072*64 floats
    float* idx = out + (size_t)NTOK * ED;  // 131072 floats

    // ws layout: s2s (4KB) | bfH (128KB) | bfL (128KB)
    char* ws = (char*)d_ws;
    float* s2s = (float*)ws;
    unsigned short* bfH = (unsigned short*)(ws + 4096);
    unsigned short* bfL = (unsigned short*)(ws + 4096 + 131072);

    vq_prep<<<64, 128, 0, stream>>>(emb, bfH, bfL, s2s);
    vq_main<<<NTOK / MBLK, TPB, 0, stream>>>(z, emb, bfH, bfL, s2s, zq, idx);
}

// Round 8
// 157.224 us; speedup vs baseline: 2.0346x; 1.0067x over previous
//
#include <hip/hip_runtime.h>

typedef short short8 __attribute__((ext_vector_type(8)));
typedef float f32x4 __attribute__((ext_vector_type(4)));

#define NTOK (8 * 16 * 32 * 32)  // 131072 tokens
#define NE 1024
#define ED 64
#define TPB 256
#define MBLK 128                 // tokens per block = 4 waves x 32
#define NMF 2                    // m-frags per wave (32 tokens)
#define WKEY (1 << 18)           // candidate window in key units (~3.9e-3 in dist)
#define SCALE (-131072.0f)       // -2^17: exact po2 scale — applied to B ONLY

__device__ __forceinline__ unsigned short bf16_rtne(float f) {
    unsigned u = __float_as_uint(f);
    return (unsigned short)((u + 0x7FFFu + ((u >> 16) & 1u)) >> 16);
}
__device__ __forceinline__ float bf16_to_f32(unsigned short h) {
    return __uint_as_float(((unsigned)h) << 16);
}

// EXACT distance — identical structure/order to the R1 kernel (absmax 0 vs numpy).
__device__ float exact_dist(const float* __restrict__ z, const float* __restrict__ emb,
                            int t, int e) {
    const float* zt = z + (size_t)t * ED;
    const float* ep = emb + (size_t)e * ED;
    float r0 = 0.f, r1 = 0.f, r2 = 0.f, r3 = 0.f;
    float r4 = 0.f, r5 = 0.f, r6 = 0.f, r7 = 0.f;
    for (int d = 0; d < ED; d += 8) {
        r0 += zt[d + 0] * zt[d + 0];
        r1 += zt[d + 1] * zt[d + 1];
        r2 += zt[d + 2] * zt[d + 2];
        r3 += zt[d + 3] * zt[d + 3];
        r4 += zt[d + 4] * zt[d + 4];
        r5 += zt[d + 5] * zt[d + 5];
        r6 += zt[d + 6] * zt[d + 6];
        r7 += zt[d + 7] * zt[d + 7];
    }
    float s1 = ((r0 + r1) + (r2 + r3)) + ((r4 + r5) + (r6 + r7));
    float q0 = 0.f, q1 = 0.f, q2 = 0.f, q3 = 0.f;
    float q4 = 0.f, q5 = 0.f, q6 = 0.f, q7 = 0.f;
    for (int d = 0; d < ED; d += 8) {
        float v0 = ep[d + 0], v1 = ep[d + 1], v2 = ep[d + 2], v3 = ep[d + 3];
        float v4 = ep[d + 4], v5 = ep[d + 5], v6 = ep[d + 6], v7 = ep[d + 7];
        q0 += v0 * v0; q1 += v1 * v1; q2 += v2 * v2; q3 += v3 * v3;
        q4 += v4 * v4; q5 += v5 * v5; q6 += v6 * v6; q7 += v7 * v7;
    }
    float s2 = ((q0 + q1) + (q2 + q3)) + ((q4 + q5) + (q6 + q7));
    float a0 = 0.f, a1 = 0.f, a2 = 0.f, a3 = 0.f;
    for (int d = 0; d < ED; d += 4) {
        a0 = fmaf(zt[d + 0], ep[d + 0], a0);
        a1 = fmaf(zt[d + 1], ep[d + 1], a1);
        a2 = fmaf(zt[d + 2], ep[d + 2], a2);
        a3 = fmaf(zt[d + 3], ep[d + 3], a3);
    }
    float g = (a0 + a1) + (a2 + a3);
    return (s1 + s2) - 2.0f * g;
}

// ---- prep: B-fragments (hi/lo bf16, pre-scaled by -2^17, MFMA-fragment order)
//      + s2s = ||e||^2 * 65536.  64 blocks x 128 thr ----
__global__ __launch_bounds__(128) void vq_prep(
    const float* __restrict__ emb,
    unsigned short* __restrict__ bfH,
    unsigned short* __restrict__ bfL,
    float* __restrict__ s2s)
{
    const int f = blockIdx.x * 128 + threadIdx.x;  // 0..8191 fragment id
    const int col = f & 15;
    const int quad = (f >> 4) & 3;
    const int kb = (f >> 6) & 1;
    const int nt = f >> 7;
    const int e = nt * 16 + col;
    const int k0 = kb * 32 + quad * 8;

    const float* p = emb + (size_t)e * ED + k0;
    float4 v0 = *(const float4*)p;
    float4 v1 = *(const float4*)(p + 4);
    float vs[8] = {v0.x, v0.y, v0.z, v0.w, v1.x, v1.y, v1.z, v1.w};
    short8 h, l;
#pragma unroll
    for (int j = 0; j < 8; ++j) {
        float x = vs[j] * SCALE;              // exact po2 scaling (B side only!)
        unsigned short hb = bf16_rtne(x);
        float hf = bf16_to_f32(hb);
        unsigned short lb = bf16_rtne(x - hf);
        h[j] = (short)hb;
        l[j] = (short)lb;
    }
    *(short8*)&bfH[(size_t)f * 8] = h;
    *(short8*)&bfL[(size_t)f * 8] = l;

    if ((f & 7) == 0) {  // 1024 s2-threads spread across all 64 blocks
        const int e2 = f >> 3;
        const float* ep = emb + (size_t)e2 * ED;
        float q0 = 0.f, q1 = 0.f, q2 = 0.f, q3 = 0.f;
        float q4 = 0.f, q5 = 0.f, q6 = 0.f, q7 = 0.f;
#pragma unroll
        for (int d = 0; d < ED; d += 8) {
            float w0 = ep[d + 0], w1 = ep[d + 1], w2 = ep[d + 2], w3 = ep[d + 3];
            float w4 = ep[d + 4], w5 = ep[d + 5], w6 = ep[d + 6], w7 = ep[d + 7];
            q0 += w0 * w0; q1 += w1 * w1; q2 += w2 * w2; q3 += w3 * w3;
            q4 += w4 * w4; q5 += w5 * w5; q6 += w6 * w6; q7 += w7 * w7;
        }
        float s2 = ((q0 + q1) + (q2 + q3)) + ((q4 + q5) + (q6 + q7));
        s2s[e2] = s2 * 65536.0f;
    }
}

// waves_per_eu(4,4): pin register budget at 128 VGPRs so the allocator stops
// economizing to 64 and thrashing hot values through AGPRs (R6/R7 disease:
// VGPR_Count=64 with ~90 live values -> v_accvgpr round-trips inflate VALU).
__global__ void __launch_bounds__(TPB)
__attribute__((amdgpu_waves_per_eu(4, 4))) vq_main(
    const float* __restrict__ z,
    const float* __restrict__ emb,
    const unsigned short* __restrict__ bfH,
    const unsigned short* __restrict__ bfL,
    const float* __restrict__ s2s_g,
    float* __restrict__ zq_out,
    float* __restrict__ idx_out)
{
    __shared__ float s2L[NE];
    __shared__ int idx_lds[MBLK];

    const int tid = threadIdx.x;
    const int lane = tid & 63;
    const int wv = __builtin_amdgcn_readfirstlane(tid >> 6);
    const int col = lane & 15;
    const int quad = lane >> 4;
    const int blockTok = blockIdx.x * MBLK;

    for (int i = tid; i < NE; i += TPB) s2L[i] = s2s_g[i];

    // ---- A-fragments: 32 tokens per wave (2 m-frags), hi/lo bf16, UNSCALED ----
    short8 Ah[NMF][2], Al[NMF][2];
#pragma unroll
    for (int mf = 0; mf < NMF; ++mf) {
#pragma unroll
        for (int kf = 0; kf < 2; ++kf) {
            const float* zp = z + (size_t)(blockTok + wv * 32 + mf * 16 + col) * ED
                              + kf * 32 + quad * 8;
            float4 v0 = *(const float4*)zp;
            float4 v1 = *(const float4*)(zp + 4);
            float vs[8] = {v0.x, v0.y, v0.z, v0.w, v1.x, v1.y, v1.z, v1.w};
            short8 h, l;
#pragma unroll
            for (int j = 0; j < 8; ++j) {
                float x = vs[j];              // NO scale on A
                unsigned short hb = bf16_rtne(x);
                float hf = bf16_to_f32(hb);
                unsigned short lb = bf16_rtne(x - hf);
                h[j] = (short)hb;
                l[j] = (short)lb;
            }
            Ah[mf][kf] = h;
            Al[mf][kf] = l;
        }
    }

    int aK[NMF][4], bK[NMF][4];
#pragma unroll
    for (int mf = 0; mf < NMF; ++mf)
#pragma unroll
        for (int r = 0; r < 4; ++r) { aK[mf][r] = 0x7FFFFFFF; bK[mf][r] = 0x7FFFFFFF; }

    __syncthreads();  // s2L ready — last barrier before the hot loop

    const short8* bh8 = (const short8*)bfH;
    const short8* bl8 = (const short8*)bfL;

    // ---- hot loop: no prefetch regs (4 waves/SIMD hide L2 latency instead) ----
#pragma unroll 2
    for (int nt = 0; nt < 64; ++nt) {
        const int base = nt * 128 + lane;
        short8 Bh0 = bh8[base], Bh1 = bh8[base + 64];  // coalesced, L1/L2-hot
        short8 Bl0 = bl8[base], Bl1 = bl8[base + 64];

        const float s2v = s2L[nt * 16 + col];
        const int e = nt * 16 + col;
#pragma unroll
        for (int mf = 0; mf < NMF; ++mf) {
            f32x4 cc = {s2v, s2v, s2v, s2v};  // acc = s2*2^16 + A·(-2^17 e) = 2^16(s2-2g)
            cc = __builtin_amdgcn_mfma_f32_16x16x32_bf16(Ah[mf][0], Bh0, cc, 0, 0, 0);
            cc = __builtin_amdgcn_mfma_f32_16x16x32_bf16(Ah[mf][1], Bh1, cc, 0, 0, 0);
            cc = __builtin_amdgcn_mfma_f32_16x16x32_bf16(Al[mf][0], Bh0, cc, 0, 0, 0);
            cc = __builtin_amdgcn_mfma_f32_16x16x32_bf16(Al[mf][1], Bh1, cc, 0, 0, 0);
            cc = __builtin_amdgcn_mfma_f32_16x16x32_bf16(Ah[mf][0], Bl0, cc, 0, 0, 0);
            cc = __builtin_amdgcn_mfma_f32_16x16x32_bf16(Ah[mf][1], Bl1, cc, 0, 0, 0);
#pragma unroll
            for (int r = 0; r < 4; ++r) {
                // no clamp: |cc| <= ~4e5 (data-bounded), key <= ~4.1e8 < 2^31;
                // v_cvt_i32_f32 saturates on any pathology.
                int key = ((int)cc[r]) * 1024 + e;  // 5-op epilogue: cvt,lshl_add,min,max,min
                int t1 = min(aK[mf][r], key);
                bK[mf][r] = min(bK[mf][r], max(aK[mf][r], key));
                aK[mf][r] = t1;
            }
        }
    }

    // ---- phase B: resolve argmin per token (16-lane groups) ----
#pragma unroll
    for (int mf = 0; mf < NMF; ++mf) {
#pragma unroll
        for (int r = 0; r < 4; ++r) {
            const int a0 = aK[mf][r], b0 = bK[mf][r];
            int A = a0, B = b0;
#pragma unroll
            for (int off = 1; off < 16; off <<= 1) {
                int A2 = __shfl_xor(A, off);
                int B2 = __shfl_xor(B, off);
                int lo = min(A, A2), hi = max(A, A2);
                B = min(min(B, B2), hi);
                A = lo;
            }
            int winner = A & 1023;
            if (B - A <= WKEY) {  // contested: exact fp32 re-check of candidates
                const int t = blockTok + wv * 32 + mf * 16 + quad * 4 + r;
                float dbest = 3.4e38f;
                int ibest = 1 << 30;
                if (a0 <= A + WKEY) {
                    int e = a0 & 1023;
                    float d = exact_dist(z, emb, t, e);
                    if (d < dbest || (d == dbest && e < ibest)) { dbest = d; ibest = e; }
                }
                if (b0 <= A + WKEY) {
                    int e = b0 & 1023;
                    float d = exact_dist(z, emb, t, e);
                    if (d < dbest || (d == dbest && e < ibest)) { dbest = d; ibest = e; }
                }
#pragma unroll
                for (int off = 1; off < 16; off <<= 1) {
                    float d2 = __shfl_xor(dbest, off);
                    int i2 = __shfl_xor(ibest, off);
                    if (d2 < dbest || (d2 == dbest && i2 < ibest)) { dbest = d2; ibest = i2; }
                }
                winner = ibest;
            }
            if (col == 0) idx_lds[wv * 32 + mf * 16 + quad * 4 + r] = winner;
        }
    }

    __syncthreads();

    // ---- outputs ----
    if (tid < MBLK) idx_out[blockTok + tid] = (float)idx_lds[tid];
    const float4* emb_f4 = (const float4*)emb;
    float4* zq_f4 = (float4*)zq_out;
#pragma unroll
    for (int i = 0; i < MBLK * 16 / TPB; ++i) {  // 8 iters
        int item = tid + i * TPB;
        int tl = item >> 4, f4 = item & 15;
        int wi = idx_lds[tl];
        zq_f4[(size_t)(blockTok + tl) * 16 + f4] = emb_f4[(size_t)wi * 16 + f4];
    }
}

extern "C" void kernel_launch(void* const* d_in, const int* in_sizes, int n_in,
                              void* d_out, int out_size, void* d_ws, size_t ws_size,
                              hipStream_t stream) {
    const float* z = (const float*)d_in[0];
    const float* emb = (const float*)d_in[1];
    float* out = (float*)d_out;
    float* zq = out;                       // 131072*64 floats
    float* idx = out + (size_t)NTOK * ED;  // 131072 floats

    // ws layout: s2s (4KB) | bfH (128KB) | bfL (128KB)
    char* ws = (char*)d_ws;
    float* s2s = (float*)ws;
    unsigned short* bfH = (unsigned short*)(ws + 4096);
    unsigned short* bfL = (unsigned short*)(ws + 4096 + 131072);

    vq_prep<<<64, 128, 0, stream>>>(emb, bfH, bfL, s2s);
    vq_main<<<NTOK / MBLK, TPB, 0, stream>>>(z, emb, bfH, bfL, s2s, zq, idx);
}

// Round 9
// 151.235 us; speedup vs baseline: 2.1152x; 1.0396x over previous
//
#include <hip/hip_runtime.h>

typedef short short8 __attribute__((ext_vector_type(8)));
typedef float f32x4 __attribute__((ext_vector_type(4)));

#define NTOK (8 * 16 * 32 * 32)  // 131072 tokens
#define NE 1024
#define ED 64
#define TPB 256
#define MBLK 128                 // tokens per block = 4 waves x 32
#define NMF 2                    // m-frags per wave (32 tokens)
#define WKEY (1 << 18)           // candidate window in key units (~3.9e-3 in dist)
#define SCALE (-131072.0f)       // -2^17: exact po2 scale — applied to B ONLY

__device__ __forceinline__ unsigned short bf16_rtne(float f) {
    unsigned u = __float_as_uint(f);
    return (unsigned short)((u + 0x7FFFu + ((u >> 16) & 1u)) >> 16);
}
__device__ __forceinline__ float bf16_to_f32(unsigned short h) {
    return __uint_as_float(((unsigned)h) << 16);
}

// EXACT distance — identical structure/order to the R1 kernel (absmax 0 vs numpy).
__device__ float exact_dist(const float* __restrict__ z, const float* __restrict__ emb,
                            int t, int e) {
    const float* zt = z + (size_t)t * ED;
    const float* ep = emb + (size_t)e * ED;
    float r0 = 0.f, r1 = 0.f, r2 = 0.f, r3 = 0.f;
    float r4 = 0.f, r5 = 0.f, r6 = 0.f, r7 = 0.f;
    for (int d = 0; d < ED; d += 8) {
        r0 += zt[d + 0] * zt[d + 0];
        r1 += zt[d + 1] * zt[d + 1];
        r2 += zt[d + 2] * zt[d + 2];
        r3 += zt[d + 3] * zt[d + 3];
        r4 += zt[d + 4] * zt[d + 4];
        r5 += zt[d + 5] * zt[d + 5];
        r6 += zt[d + 6] * zt[d + 6];
        r7 += zt[d + 7] * zt[d + 7];
    }
    float s1 = ((r0 + r1) + (r2 + r3)) + ((r4 + r5) + (r6 + r7));
    float q0 = 0.f, q1 = 0.f, q2 = 0.f, q3 = 0.f;
    float q4 = 0.f, q5 = 0.f, q6 = 0.f, q7 = 0.f;
    for (int d = 0; d < ED; d += 8) {
        float v0 = ep[d + 0], v1 = ep[d + 1], v2 = ep[d + 2], v3 = ep[d + 3];
        float v4 = ep[d + 4], v5 = ep[d + 5], v6 = ep[d + 6], v7 = ep[d + 7];
        q0 += v0 * v0; q1 += v1 * v1; q2 += v2 * v2; q3 += v3 * v3;
        q4 += v4 * v4; q5 += v5 * v5; q6 += v6 * v6; q7 += v7 * v7;
    }
    float s2 = ((q0 + q1) + (q2 + q3)) + ((q4 + q5) + (q6 + q7));
    float a0 = 0.f, a1 = 0.f, a2 = 0.f, a3 = 0.f;
    for (int d = 0; d < ED; d += 4) {
        a0 = fmaf(zt[d + 0], ep[d + 0], a0);
        a1 = fmaf(zt[d + 1], ep[d + 1], a1);
        a2 = fmaf(zt[d + 2], ep[d + 2], a2);
        a3 = fmaf(zt[d + 3], ep[d + 3], a3);
    }
    float g = (a0 + a1) + (a2 + a3);
    return (s1 + s2) - 2.0f * g;
}

// ---- prep: B-fragments (hi/lo bf16, -2^17-scaled, MFMA-fragment order) and
//      COALESCED s2 (4 lanes per row, float4 loads, shuffle combine).
//      s2 summation order differs from numpy — safe: s2s feeds approx keys
//      only; exact_dist recomputes s2 exactly. ----
__global__ __launch_bounds__(128) void vq_prep(
    const float* __restrict__ emb,
    unsigned short* __restrict__ bfH,
    unsigned short* __restrict__ bfL,
    float* __restrict__ s2s)
{
    const int f = blockIdx.x * 128 + threadIdx.x;  // 0..8191 fragment id
    const int col = f & 15;
    const int quad = (f >> 4) & 3;
    const int kb = (f >> 6) & 1;
    const int nt = f >> 7;
    const int e = nt * 16 + col;
    const int k0 = kb * 32 + quad * 8;

    const float* p = emb + (size_t)e * ED + k0;
    float4 v0 = *(const float4*)p;
    float4 v1 = *(const float4*)(p + 4);
    float vs[8] = {v0.x, v0.y, v0.z, v0.w, v1.x, v1.y, v1.z, v1.w};
    short8 h, l;
#pragma unroll
    for (int j = 0; j < 8; ++j) {
        float x = vs[j] * SCALE;              // exact po2 scaling (B side only!)
        unsigned short hb = bf16_rtne(x);
        float hf = bf16_to_f32(hb);
        unsigned short lb = bf16_rtne(x - hf);
        h[j] = (short)hb;
        l[j] = (short)lb;
    }
    *(short8*)&bfH[(size_t)f * 8] = h;
    *(short8*)&bfL[(size_t)f * 8] = l;

    // s2: threads 0..4095 -> (row = f>>2, seg = f&3), 16 floats each, coalesced
    if (f < 4096) {
        const int row = f >> 2;
        const float4* rp = (const float4*)(emb + (size_t)row * ED + (f & 3) * 16);
        float4 a = rp[0], b = rp[1], c = rp[2], d = rp[3];
        float s = a.x * a.x + a.y * a.y + a.z * a.z + a.w * a.w
                + b.x * b.x + b.y * b.y + b.z * b.z + b.w * b.w
                + c.x * c.x + c.y * c.y + c.z * c.z + c.w * c.w
                + d.x * d.x + d.y * d.y + d.z * d.z + d.w * d.w;
        s += __shfl_xor(s, 1);
        s += __shfl_xor(s, 2);
        if ((f & 3) == 0) s2s[row] = s * 65536.0f;
    }
}

// LDS double-buffered B staging: 4 KB/nt slice shared by all 4 waves
// (cuts global B traffic 4x and hides load latency behind the dbuf).
__global__ void __launch_bounds__(TPB)
__attribute__((amdgpu_waves_per_eu(4, 4))) vq_main(
    const float* __restrict__ z,
    const float* __restrict__ emb,
    const unsigned short* __restrict__ bfH,
    const unsigned short* __restrict__ bfL,
    const float* __restrict__ s2s_g,
    float* __restrict__ zq_out,
    float* __restrict__ idx_out)
{
    __shared__ float s2L[NE];
    __shared__ int idx_lds[MBLK];
    __shared__ uint4 Bbuf[2][256];  // [buf][chunk]: 128 hi-chunks then 128 lo-chunks

    const int tid = threadIdx.x;
    const int lane = tid & 63;
    const int wv = __builtin_amdgcn_readfirstlane(tid >> 6);
    const int col = lane & 15;
    const int quad = lane >> 4;
    const int blockTok = blockIdx.x * MBLK;

    for (int i = tid; i < NE; i += TPB) s2L[i] = s2s_g[i];

    // staging role: waves 0,1 move bfH slice, waves 2,3 move bfL (wave-uniform)
    const uint4* src = (const uint4*)(tid < 128 ? bfH : bfL);
    const int chunk = tid & 127;
    const int dstc = (tid >> 7) * 128 + chunk;

    // ---- A-fragments: 32 tokens per wave (2 m-frags), hi/lo bf16, UNSCALED ----
    short8 Ah[NMF][2], Al[NMF][2];
#pragma unroll
    for (int mf = 0; mf < NMF; ++mf) {
#pragma unroll
        for (int kf = 0; kf < 2; ++kf) {
            const float* zp = z + (size_t)(blockTok + wv * 32 + mf * 16 + col) * ED
                              + kf * 32 + quad * 8;
            float4 v0 = *(const float4*)zp;
            float4 v1 = *(const float4*)(zp + 4);
            float vs[8] = {v0.x, v0.y, v0.z, v0.w, v1.x, v1.y, v1.z, v1.w};
            short8 h, l;
#pragma unroll
            for (int j = 0; j < 8; ++j) {
                float x = vs[j];              // NO scale on A
                unsigned short hb = bf16_rtne(x);
                float hf = bf16_to_f32(hb);
                unsigned short lb = bf16_rtne(x - hf);
                h[j] = (short)hb;
                l[j] = (short)lb;
            }
            Ah[mf][kf] = h;
            Al[mf][kf] = l;
        }
    }

    int aK[NMF][4], bK[NMF][4];
#pragma unroll
    for (int mf = 0; mf < NMF; ++mf)
#pragma unroll
        for (int r = 0; r < 4; ++r) { aK[mf][r] = 0x7FFFFFFF; bK[mf][r] = 0x7FFFFFFF; }

    // stage nt=0 into buf 0
    Bbuf[0][dstc] = src[chunk];
    __syncthreads();  // s2L + buf0 ready

    int p = 0;
    for (int nt = 0; nt < 64; ++nt) {
        // issue next slice's global load early (latency overlapped w/ compute)
        uint4 nv;
        if (nt < 63) nv = src[(nt + 1) * 128 + chunk];

        const short8* bp = (const short8*)Bbuf[p];
        short8 Bh0 = bp[lane];        // all 4 waves broadcast-read the same slice
        short8 Bh1 = bp[64 + lane];
        short8 Bl0 = bp[128 + lane];
        short8 Bl1 = bp[192 + lane];

        const float s2v = s2L[nt * 16 + col];
        const int e = nt * 16 + col;
#pragma unroll
        for (int mf = 0; mf < NMF; ++mf) {
            f32x4 cc = {s2v, s2v, s2v, s2v};  // acc = s2*2^16 + A·(-2^17 e) = 2^16(s2-2g)
            cc = __builtin_amdgcn_mfma_f32_16x16x32_bf16(Ah[mf][0], Bh0, cc, 0, 0, 0);
            cc = __builtin_amdgcn_mfma_f32_16x16x32_bf16(Ah[mf][1], Bh1, cc, 0, 0, 0);
            cc = __builtin_amdgcn_mfma_f32_16x16x32_bf16(Al[mf][0], Bh0, cc, 0, 0, 0);
            cc = __builtin_amdgcn_mfma_f32_16x16x32_bf16(Al[mf][1], Bh1, cc, 0, 0, 0);
            cc = __builtin_amdgcn_mfma_f32_16x16x32_bf16(Ah[mf][0], Bl0, cc, 0, 0, 0);
            cc = __builtin_amdgcn_mfma_f32_16x16x32_bf16(Ah[mf][1], Bl1, cc, 0, 0, 0);
#pragma unroll
            for (int r = 0; r < 4; ++r) {
                int key = ((int)cc[r]) * 1024 + e;  // unique, monotone, tie->low e
                int t1 = min(aK[mf][r], key);
                bK[mf][r] = min(bK[mf][r], max(aK[mf][r], key));
                aK[mf][r] = t1;
            }
        }

        if (nt < 63) Bbuf[p ^ 1][dstc] = nv;  // write other buffer
        __syncthreads();
        p ^= 1;
    }

    // ---- phase B: resolve argmin per token (16-lane groups) ----
#pragma unroll
    for (int mf = 0; mf < NMF; ++mf) {
#pragma unroll
        for (int r = 0; r < 4; ++r) {
            const int a0 = aK[mf][r], b0 = bK[mf][r];
            int A = a0, B = b0;
#pragma unroll
            for (int off = 1; off < 16; off <<= 1) {
                int A2 = __shfl_xor(A, off);
                int B2 = __shfl_xor(B, off);
                int lo = min(A, A2), hi = max(A, A2);
                B = min(min(B, B2), hi);
                A = lo;
            }
            int winner = A & 1023;
            if (B - A <= WKEY) {  // contested: exact fp32 re-check of candidates
                const int t = blockTok + wv * 32 + mf * 16 + quad * 4 + r;
                float dbest = 3.4e38f;
                int ibest = 1 << 30;
                if (a0 <= A + WKEY) {
                    int e = a0 & 1023;
                    float d = exact_dist(z, emb, t, e);
                    if (d < dbest || (d == dbest && e < ibest)) { dbest = d; ibest = e; }
                }
                if (b0 <= A + WKEY) {
                    int e = b0 & 1023;
                    float d = exact_dist(z, emb, t, e);
                    if (d < dbest || (d == dbest && e < ibest)) { dbest = d; ibest = e; }
                }
#pragma unroll
                for (int off = 1; off < 16; off <<= 1) {
                    float d2 = __shfl_xor(dbest, off);
                    int i2 = __shfl_xor(ibest, off);
                    if (d2 < dbest || (d2 == dbest && i2 < ibest)) { dbest = d2; ibest = i2; }
                }
                winner = ibest;
            }
            if (col == 0) idx_lds[wv * 32 + mf * 16 + quad * 4 + r] = winner;
        }
    }

    __syncthreads();

    // ---- outputs ----
    if (tid < MBLK) idx_out[blockTok + tid] = (float)idx_lds[tid];
    const float4* emb_f4 = (const float4*)emb;
    float4* zq_f4 = (float4*)zq_out;
#pragma unroll
    for (int i = 0; i < MBLK * 16 / TPB; ++i) {  // 8 iters
        int item = tid + i * TPB;
        int tl = item >> 4, f4 = item & 15;
        int wi = idx_lds[tl];
        zq_f4[(size_t)(blockTok + tl) * 16 + f4] = emb_f4[(size_t)wi * 16 + f4];
    }
}

extern "C" void kernel_launch(void* const* d_in, const int* in_sizes, int n_in,
                              void* d_out, int out_size, void* d_ws, size_t ws_size,
                              hipStream_t stream) {
    const float* z = (const float*)d_in[0];
    const float* emb = (const float*)d_in[1];
    float* out = (float*)d_out;
    float* zq = out;                       // 131072*64 floats
    float* idx = out + (size_t)NTOK * ED;  // 131072 floats

    // ws layout: s2s (4KB) | bfH (128KB) | bfL (128KB)
    char* ws = (char*)d_ws;
    float* s2s = (float*)ws;
    unsigned short* bfH = (unsigned short*)(ws + 4096);
    unsigned short* bfL = (unsigned short*)(ws + 4096 + 131072);

    vq_prep<<<64, 128, 0, stream>>>(emb, bfH, bfL, s2s);
    vq_main<<<NTOK / MBLK, TPB, 0, stream>>>(z, emb, bfH, bfL, s2s, zq, idx);
}